// Round 4
// baseline (121.527 us; speedup 1.0000x reference)
//
#include <hip/hip_runtime.h>

// RegionSelection: bilinear 2x upsample of attention map (8,1,80,80)->(8,1,160,160),
// per-batch rank-1921 threshold (k=int(0.3*6400)=1920, threshold=topv[:,k]),
// mask = up >= thr, weighted = local_feat*(mask+0.1).
// Outputs concatenated: weighted (8*256*160*160 fp32) then mask (8*160*160 fp32).

#define NIN   6400    // 80*80
#define NUP   25600   // 160*160
#define KRANK 1921u   // (k+1)-th largest == topv[:, k]

typedef float f32x4 __attribute__((ext_vector_type(4)));

// Wave-parallel "find bin containing rank `rem_in` counting from the top" over
// NBINS histogram bins. Two-level: 64 chunk sums + shfl suffix-scan, then a
// parallel scan of the selected chunk's bins. No serial dependent-LDS chains.
// Executed by wave 0 (tid<64); writes {bin, remaining-within-bin} to s_bcast.
template <int NBINS>
__device__ inline void find_bin(const unsigned* s_hist, unsigned rem_in,
                                unsigned* s_bcast, int tid)
{
    constexpr int CHUNK = NBINS / 64;
    if (tid < 64) {
        const int lane = tid;
        // level 1: per-lane chunk sums (independent LDS reads, pipelined)
        unsigned csum = 0;
        #pragma unroll
        for (int k = 0; k < CHUNK; ++k) csum += s_hist[lane * CHUNK + k];
        // inclusive suffix sum across lanes: suff[l] = sum csum[l..63]
        unsigned suff = csum;
        #pragma unroll
        for (int off = 1; off < 64; off <<= 1) {
            unsigned o = __shfl_down(suff, off);
            if (lane + off < 64) suff += o;
        }
        unsigned suff_next = __shfl_down(suff, 1);
        if (lane == 63) suff_next = 0;
        const bool hit = (suff >= rem_in) & (suff_next < rem_in);  // exactly one lane
        unsigned long long bmask = __ballot(hit);
        const int src = (int)__builtin_ctzll(bmask);
        const unsigned r_chunk  = __shfl(rem_in - suff_next, src); // rank within chunk (from top)
        const int      cbase    = src * CHUNK;
        // level 2: lanes 0..CHUNK-1 scan the chunk's bins in parallel
        unsigned h = (lane < CHUNK) ? s_hist[cbase + lane] : 0u;
        unsigned ssum = h;
        #pragma unroll
        for (int off = 1; off < CHUNK; off <<= 1) {
            unsigned o = __shfl_down(ssum, off);
            if (lane + off < CHUNK) ssum += o;
        }
        unsigned ssum_next = __shfl_down(ssum, 1);
        if (lane >= CHUNK - 1) ssum_next = 0;
        const bool hit2 = (lane < CHUNK) & (ssum >= r_chunk) & (ssum_next < r_chunk);
        if (hit2) {
            s_bcast[0] = (unsigned)(cbase + lane);
            s_bcast[1] = r_chunk - ssum_next;
        }
    }
}

__global__ __launch_bounds__(1024) void upsample_select_kernel(
    const float* __restrict__ att, float* __restrict__ mask_out)
{
    __shared__ float    s_in[NIN];
    __shared__ unsigned s_hist[2048];
    __shared__ unsigned s_bcast[2];

    const int b   = blockIdx.x;
    const int tid = threadIdx.x;

    const float* in = att + b * NIN;
    for (int i = tid; i < NIN; i += 1024) s_in[i] = in[i];
    __syncthreads();

    // bilinear 2x upsample, half-pixel centers; weights exactly {0.75,0.25};
    // boundary rows/cols clamp to the edge pixel. (validated absmax==0)
    unsigned ub[25];
    #pragma unroll
    for (int j = 0; j < 25; ++j) {
        int i = j * 1024 + tid;
        int r = i / 160;
        int c = i - r * 160;
        int y0, y1; float wy;
        if (r == 0)        { y0 = 0;  y1 = 0;  wy = 0.0f; }
        else if (r == 159) { y0 = 79; y1 = 79; wy = 0.0f; }
        else { float y = 0.5f * (float)r - 0.25f; y0 = (int)y; y1 = y0 + 1; wy = y - (float)y0; }
        int x0, x1; float wx;
        if (c == 0)        { x0 = 0;  x1 = 0;  wx = 0.0f; }
        else if (c == 159) { x0 = 79; x1 = 79; wx = 0.0f; }
        else { float x = 0.5f * (float)c - 0.25f; x0 = (int)x; x1 = x0 + 1; wx = x - (float)x0; }
        float top = s_in[y0 * 80 + x0] * (1.0f - wx) + s_in[y0 * 80 + x1] * wx;
        float bot = s_in[y1 * 80 + x0] * (1.0f - wx) + s_in[y1 * 80 + x1] * wx;
        float v   = top * (1.0f - wy) + bot * wy;
        ub[j] = __float_as_uint(v);   // v in [0,1) -> uint order == float order
    }

    // ---- exact radix select, 3 passes: bits [30:20], [19:10], [9:0] ----
    for (int i = tid; i < 2048; i += 1024) s_hist[i] = 0;
    __syncthreads();
    #pragma unroll
    for (int j = 0; j < 25; ++j) atomicAdd(&s_hist[ub[j] >> 20], 1u);  // <0x3F8 < 2048
    __syncthreads();
    find_bin<2048>(s_hist, KRANK, s_bcast, tid);
    __syncthreads();
    const unsigned p1  = s_bcast[0];
    unsigned       rem = s_bcast[1];
    __syncthreads();

    for (int i = tid; i < 1024; i += 1024) s_hist[i] = 0;
    __syncthreads();
    #pragma unroll
    for (int j = 0; j < 25; ++j) {
        unsigned u = ub[j];
        if ((u >> 20) == p1) atomicAdd(&s_hist[(u >> 10) & 1023u], 1u);
    }
    __syncthreads();
    find_bin<1024>(s_hist, rem, s_bcast, tid);
    __syncthreads();
    const unsigned pref2 = (p1 << 10) | s_bcast[0];
    rem = s_bcast[1];
    __syncthreads();

    for (int i = tid; i < 1024; i += 1024) s_hist[i] = 0;
    __syncthreads();
    #pragma unroll
    for (int j = 0; j < 25; ++j) {
        unsigned u = ub[j];
        if ((u >> 10) == pref2) atomicAdd(&s_hist[u & 1023u], 1u);
    }
    __syncthreads();
    find_bin<1024>(s_hist, rem, s_bcast, tid);
    __syncthreads();
    const unsigned thr_bits = (pref2 << 10) | s_bcast[0];

    // mask: same values, same >= comparison as reference -> identical set
    float* mptr = mask_out + b * NUP;
    #pragma unroll
    for (int j = 0; j < 25; ++j)
        mptr[j * 1024 + tid] = (ub[j] >= thr_bits) ? 1.0f : 0.0f;
}

// weighted = local_feat * (mask + 0.1).
// One mask load per thread -> weight in registers, then stream CH channels
// (stride 6400 f32x4). Plain loads/stores (m13's 6.29 TB/s copy pattern).
#define CH 32
__global__ __launch_bounds__(256) void apply_mask_kernel(
    const f32x4* __restrict__ feat, const f32x4* __restrict__ mask,
    f32x4* __restrict__ out)
{
    const int hw4 = blockIdx.x * 256 + threadIdx.x;   // 0..6399 within plane
    const int b   = blockIdx.y;
    const int c0  = blockIdx.z * CH;

    f32x4 w = mask[b * 6400 + hw4] + 0.1f;

    const int base = (b * 256 + c0) * 6400 + hw4;
    const f32x4* fp = feat + base;
    f32x4*       op = out  + base;

    #pragma unroll 16
    for (int c = 0; c < CH; ++c) {
        f32x4 v = fp[c * 6400];
        v *= w;
        op[c * 6400] = v;
    }
}

extern "C" void kernel_launch(void* const* d_in, const int* in_sizes, int n_in,
                              void* d_out, int out_size, void* d_ws, size_t ws_size,
                              hipStream_t stream)
{
    const float* local_feat = (const float*)d_in[0];   // (8,256,160,160) fp32
    const float* att        = (const float*)d_in[1];   // (8,1,80,80) fp32
    // d_in[2] = spatial_scale (==2, fixed by problem shapes)

    float* out      = (float*)d_out;
    float* mask_out = out + 8 * 256 * 160 * 160;       // second output region

    upsample_select_kernel<<<8, 1024, 0, stream>>>(att, mask_out);

    dim3 grid(25, 8, 256 / CH);
    apply_mask_kernel<<<grid, 256, 0, stream>>>(
        (const f32x4*)local_feat, (const f32x4*)mask_out, (f32x4*)out);
}

// Round 5
// 104.356 us; speedup vs baseline: 1.1645x; 1.1645x over previous
//
#include <hip/hip_runtime.h>

// RegionSelection: bilinear 2x upsample of attention map (8,1,80,80)->(8,1,160,160),
// per-batch rank-1921 threshold (k=int(0.3*6400)=1920, threshold=topv[:,k]),
// mask = up >= thr, weighted = local_feat*(mask+0.1).
// Outputs concatenated: weighted (8*256*160*160 fp32) then mask (8*160*160 fp32).

#define NIN   6400    // 80*80
#define NUP   25600   // 160*160
#define KRANK 1921u   // (k+1)-th largest == topv[:, k]

typedef float f32x4 __attribute__((ext_vector_type(4)));

// Wave-parallel "find bin containing rank `rem_in` counting from the top" over
// NBINS histogram bins. Two-level: 64 chunk sums + shfl suffix-scan, then a
// parallel scan of the selected chunk's bins. No serial dependent-LDS chains.
// Executed by wave 0 (tid<64); writes {bin, remaining-within-bin} to s_bcast.
template <int NBINS>
__device__ inline void find_bin(const unsigned* s_hist, unsigned rem_in,
                                unsigned* s_bcast, int tid)
{
    constexpr int CHUNK = NBINS / 64;
    if (tid < 64) {
        const int lane = tid;
        unsigned csum = 0;
        #pragma unroll
        for (int k = 0; k < CHUNK; ++k) csum += s_hist[lane * CHUNK + k];
        unsigned suff = csum;                     // suffix sum: suff[l] = sum csum[l..63]
        #pragma unroll
        for (int off = 1; off < 64; off <<= 1) {
            unsigned o = __shfl_down(suff, off);
            if (lane + off < 64) suff += o;
        }
        unsigned suff_next = __shfl_down(suff, 1);
        if (lane == 63) suff_next = 0;
        const bool hit = (suff >= rem_in) & (suff_next < rem_in);  // exactly one lane
        unsigned long long bmask = __ballot(hit);
        const int src = (int)__builtin_ctzll(bmask);
        const unsigned r_chunk = __shfl(rem_in - suff_next, src);  // rank within chunk
        const int      cbase   = src * CHUNK;
        unsigned h = (lane < CHUNK) ? s_hist[cbase + lane] : 0u;
        unsigned ssum = h;
        #pragma unroll
        for (int off = 1; off < CHUNK; off <<= 1) {
            unsigned o = __shfl_down(ssum, off);
            if (lane + off < CHUNK) ssum += o;
        }
        unsigned ssum_next = __shfl_down(ssum, 1);
        if (lane >= CHUNK - 1) ssum_next = 0;
        const bool hit2 = (lane < CHUNK) & (ssum >= r_chunk) & (ssum_next < r_chunk);
        if (hit2) {
            s_bcast[0] = (unsigned)(cbase + lane);
            s_bcast[1] = r_chunk - ssum_next;
        }
    }
}

__global__ __launch_bounds__(1024) void upsample_select_kernel(
    const float* __restrict__ att, float* __restrict__ mask_out)
{
    __shared__ float    s_in[NIN];
    __shared__ unsigned s_hist[2048];
    __shared__ unsigned s_bcast[2];

    const int b   = blockIdx.x;
    const int tid = threadIdx.x;

    const float* in = att + b * NIN;
    for (int i = tid; i < NIN; i += 1024) s_in[i] = in[i];
    __syncthreads();

    // bilinear 2x upsample, half-pixel centers; weights exactly {0.75,0.25};
    // boundary rows/cols clamp to the edge pixel. (validated absmax==0)
    unsigned ub[25];
    #pragma unroll
    for (int j = 0; j < 25; ++j) {
        int i = j * 1024 + tid;
        int r = i / 160;
        int c = i - r * 160;
        int y0, y1; float wy;
        if (r == 0)        { y0 = 0;  y1 = 0;  wy = 0.0f; }
        else if (r == 159) { y0 = 79; y1 = 79; wy = 0.0f; }
        else { float y = 0.5f * (float)r - 0.25f; y0 = (int)y; y1 = y0 + 1; wy = y - (float)y0; }
        int x0, x1; float wx;
        if (c == 0)        { x0 = 0;  x1 = 0;  wx = 0.0f; }
        else if (c == 159) { x0 = 79; x1 = 79; wx = 0.0f; }
        else { float x = 0.5f * (float)c - 0.25f; x0 = (int)x; x1 = x0 + 1; wx = x - (float)x0; }
        float top = s_in[y0 * 80 + x0] * (1.0f - wx) + s_in[y0 * 80 + x1] * wx;
        float bot = s_in[y1 * 80 + x0] * (1.0f - wx) + s_in[y1 * 80 + x1] * wx;
        float v   = top * (1.0f - wy) + bot * wy;
        ub[j] = __float_as_uint(v);   // v in [0,1) -> uint order == float order
    }

    // ---- exact radix select, 3 passes: bits [30:20], [19:10], [9:0] ----
    for (int i = tid; i < 2048; i += 1024) s_hist[i] = 0;
    __syncthreads();
    #pragma unroll
    for (int j = 0; j < 25; ++j) atomicAdd(&s_hist[ub[j] >> 20], 1u);  // <0x3F8 < 2048
    __syncthreads();
    find_bin<2048>(s_hist, KRANK, s_bcast, tid);
    __syncthreads();
    const unsigned p1  = s_bcast[0];
    unsigned       rem = s_bcast[1];
    __syncthreads();

    for (int i = tid; i < 1024; i += 1024) s_hist[i] = 0;
    __syncthreads();
    #pragma unroll
    for (int j = 0; j < 25; ++j) {
        unsigned u = ub[j];
        if ((u >> 20) == p1) atomicAdd(&s_hist[(u >> 10) & 1023u], 1u);
    }
    __syncthreads();
    find_bin<1024>(s_hist, rem, s_bcast, tid);
    __syncthreads();
    const unsigned pref2 = (p1 << 10) | s_bcast[0];
    rem = s_bcast[1];
    __syncthreads();

    for (int i = tid; i < 1024; i += 1024) s_hist[i] = 0;
    __syncthreads();
    #pragma unroll
    for (int j = 0; j < 25; ++j) {
        unsigned u = ub[j];
        if ((u >> 10) == pref2) atomicAdd(&s_hist[u & 1023u], 1u);
    }
    __syncthreads();
    find_bin<1024>(s_hist, rem, s_bcast, tid);
    __syncthreads();
    const unsigned thr_bits = (pref2 << 10) | s_bcast[0];

    // mask: same values, same >= comparison as reference -> identical set
    float* mptr = mask_out + b * NUP;
    #pragma unroll
    for (int j = 0; j < 25; ++j)
        mptr[j * 1024 + tid] = (ub[j] >= thr_bits) ? 1.0f : 0.0f;
}

// weighted = local_feat * (mask + 0.1).
// Contiguous plane streaming: one block per (b,c) plane, 25 fully-coalesced
// f32x4 iterations (m13 copy pattern). Mask plane streams from L2 (256x
// reuse across channel-blocks). nt on feat/out keeps L2 free for the mask
// (round-3 vs round-4 A/B: nt was +15% on this workload).
__global__ __launch_bounds__(256) void apply_mask_kernel(
    const f32x4* __restrict__ feat, const f32x4* __restrict__ mask,
    f32x4* __restrict__ out)
{
    const int tid   = threadIdx.x;
    const int plane = blockIdx.x;          // b*256 + c
    const int b     = plane >> 8;

    const f32x4* mp = mask + b * 6400 + tid;
    const f32x4* fp = feat + plane * 6400 + tid;
    f32x4*       op = out  + plane * 6400 + tid;

    #pragma unroll 5
    for (int i = 0; i < 25; ++i) {
        f32x4 m = mp[i * 256];
        f32x4 v = __builtin_nontemporal_load(fp + i * 256);
        v *= (m + 0.1f);
        __builtin_nontemporal_store(v, op + i * 256);
    }
}

extern "C" void kernel_launch(void* const* d_in, const int* in_sizes, int n_in,
                              void* d_out, int out_size, void* d_ws, size_t ws_size,
                              hipStream_t stream)
{
    const float* local_feat = (const float*)d_in[0];   // (8,256,160,160) fp32
    const float* att        = (const float*)d_in[1];   // (8,1,80,80) fp32
    // d_in[2] = spatial_scale (==2, fixed by problem shapes)

    float* out      = (float*)d_out;
    float* mask_out = out + 8 * 256 * 160 * 160;       // second output region

    upsample_select_kernel<<<8, 1024, 0, stream>>>(att, mask_out);

    apply_mask_kernel<<<2048, 256, 0, stream>>>(
        (const f32x4*)local_feat, (const f32x4*)mask_out, (f32x4*)out);
}

// Round 6
// 103.581 us; speedup vs baseline: 1.1732x; 1.0075x over previous
//
#include <hip/hip_runtime.h>

// RegionSelection: bilinear 2x upsample of attention map (8,1,80,80)->(8,1,160,160),
// per-batch rank-1921 threshold (k=int(0.3*6400)=1920, threshold=topv[:,k]),
// mask = up >= thr, weighted = local_feat*(mask+0.1).
// Outputs concatenated: weighted (8*256*160*160 fp32) then mask (8*160*160 fp32).
// d_ws: bit-packed mask, 400 ull per batch (1 bit per upsampled element).

#define NIN   6400    // 80*80
#define NUP   25600   // 160*160
#define KRANK 1921u   // (k+1)-th largest == topv[:, k]

typedef float f32x4 __attribute__((ext_vector_type(4)));

// Wave-parallel "find bin containing rank `rem_in` counting from the top" over
// NBINS histogram bins. Two-level: 64 chunk sums + shfl suffix-scan, then a
// parallel scan of the selected chunk's bins. No serial dependent-LDS chains.
// Executed by wave 0 (tid<64); writes {bin, remaining-within-bin} to s_bcast.
template <int NBINS>
__device__ inline void find_bin(const unsigned* s_hist, unsigned rem_in,
                                unsigned* s_bcast, int tid)
{
    constexpr int CHUNK = NBINS / 64;
    if (tid < 64) {
        const int lane = tid;
        unsigned csum = 0;
        #pragma unroll
        for (int k = 0; k < CHUNK; ++k) csum += s_hist[lane * CHUNK + k];
        unsigned suff = csum;                     // suffix sum: suff[l] = sum csum[l..63]
        #pragma unroll
        for (int off = 1; off < 64; off <<= 1) {
            unsigned o = __shfl_down(suff, off);
            if (lane + off < 64) suff += o;
        }
        unsigned suff_next = __shfl_down(suff, 1);
        if (lane == 63) suff_next = 0;
        const bool hit = (suff >= rem_in) & (suff_next < rem_in);  // exactly one lane
        unsigned long long bmask = __ballot(hit);
        const int src = (int)__builtin_ctzll(bmask);
        const unsigned r_chunk = __shfl(rem_in - suff_next, src);  // rank within chunk
        const int      cbase   = src * CHUNK;
        unsigned h = (lane < CHUNK) ? s_hist[cbase + lane] : 0u;
        unsigned ssum = h;
        #pragma unroll
        for (int off = 1; off < CHUNK; off <<= 1) {
            unsigned o = __shfl_down(ssum, off);
            if (lane + off < CHUNK) ssum += o;
        }
        unsigned ssum_next = __shfl_down(ssum, 1);
        if (lane >= CHUNK - 1) ssum_next = 0;
        const bool hit2 = (lane < CHUNK) & (ssum >= r_chunk) & (ssum_next < r_chunk);
        if (hit2) {
            s_bcast[0] = (unsigned)(cbase + lane);
            s_bcast[1] = r_chunk - ssum_next;
        }
    }
}

__global__ __launch_bounds__(1024) void upsample_select_kernel(
    const float* __restrict__ att, float* __restrict__ mask_out,
    unsigned long long* __restrict__ ws_bits)
{
    __shared__ float    s_in[NIN];
    __shared__ unsigned s_hist[2048];
    __shared__ unsigned s_bcast[2];

    const int b   = blockIdx.x;
    const int tid = threadIdx.x;

    const float* in = att + b * NIN;
    for (int i = tid; i < NIN; i += 1024) s_in[i] = in[i];
    __syncthreads();

    // bilinear 2x upsample, half-pixel centers; weights exactly {0.75,0.25};
    // boundary rows/cols clamp to the edge pixel. (validated absmax==0)
    unsigned ub[25];
    #pragma unroll
    for (int j = 0; j < 25; ++j) {
        int i = j * 1024 + tid;
        int r = i / 160;
        int c = i - r * 160;
        int y0, y1; float wy;
        if (r == 0)        { y0 = 0;  y1 = 0;  wy = 0.0f; }
        else if (r == 159) { y0 = 79; y1 = 79; wy = 0.0f; }
        else { float y = 0.5f * (float)r - 0.25f; y0 = (int)y; y1 = y0 + 1; wy = y - (float)y0; }
        int x0, x1; float wx;
        if (c == 0)        { x0 = 0;  x1 = 0;  wx = 0.0f; }
        else if (c == 159) { x0 = 79; x1 = 79; wx = 0.0f; }
        else { float x = 0.5f * (float)c - 0.25f; x0 = (int)x; x1 = x0 + 1; wx = x - (float)x0; }
        float top = s_in[y0 * 80 + x0] * (1.0f - wx) + s_in[y0 * 80 + x1] * wx;
        float bot = s_in[y1 * 80 + x0] * (1.0f - wx) + s_in[y1 * 80 + x1] * wx;
        float v   = top * (1.0f - wy) + bot * wy;
        ub[j] = __float_as_uint(v);   // v in [0,1) -> uint order == float order
    }

    // ---- exact radix select, 3 passes: bits [30:20], [19:10], [9:0] ----
    for (int i = tid; i < 2048; i += 1024) s_hist[i] = 0;
    __syncthreads();
    #pragma unroll
    for (int j = 0; j < 25; ++j) atomicAdd(&s_hist[ub[j] >> 20], 1u);  // <0x3F8 < 2048
    __syncthreads();
    find_bin<2048>(s_hist, KRANK, s_bcast, tid);
    __syncthreads();
    const unsigned p1  = s_bcast[0];
    unsigned       rem = s_bcast[1];
    __syncthreads();

    for (int i = tid; i < 1024; i += 1024) s_hist[i] = 0;
    __syncthreads();
    #pragma unroll
    for (int j = 0; j < 25; ++j) {
        unsigned u = ub[j];
        if ((u >> 20) == p1) atomicAdd(&s_hist[(u >> 10) & 1023u], 1u);
    }
    __syncthreads();
    find_bin<1024>(s_hist, rem, s_bcast, tid);
    __syncthreads();
    const unsigned pref2 = (p1 << 10) | s_bcast[0];
    rem = s_bcast[1];
    __syncthreads();

    for (int i = tid; i < 1024; i += 1024) s_hist[i] = 0;
    __syncthreads();
    #pragma unroll
    for (int j = 0; j < 25; ++j) {
        unsigned u = ub[j];
        if ((u >> 10) == pref2) atomicAdd(&s_hist[u & 1023u], 1u);
    }
    __syncthreads();
    find_bin<1024>(s_hist, rem, s_bcast, tid);
    __syncthreads();
    const unsigned thr_bits = (pref2 << 10) | s_bcast[0];

    // mask outputs: fp32 plane (required output) + bit-packed plane (for the
    // streaming kernel). Same values, same >= comparison -> identical set.
    float*              mptr  = mask_out + b * NUP;
    unsigned long long* wbptr = ws_bits + b * 400;   // 400 ull = 25600 bits
    const int lane = tid & 63;
    const int wv   = tid >> 6;
    #pragma unroll
    for (int j = 0; j < 25; ++j) {
        const bool sel = (ub[j] >= thr_bits);
        mptr[j * 1024 + tid] = sel ? 1.0f : 0.0f;
        unsigned long long bal = __ballot(sel);     // bit i = element j*1024+wv*64+i
        if (lane == 0) wbptr[j * 16 + wv] = bal;
    }
}

// weighted = local_feat * (mask + 0.1).
// One block per (b,c) plane; plane's bit-packed mask preloaded into LDS
// (3.2 KB), so the stream is pure {global load, ds_read broadcast, store} --
// the m13 copy shape. nt on feat/out (round-3/4 A/B: +15%).
__global__ __launch_bounds__(256) void apply_mask_kernel(
    const f32x4* __restrict__ feat, const unsigned* __restrict__ bits,
    f32x4* __restrict__ out)
{
    __shared__ unsigned s_bits[800];

    const int tid   = threadIdx.x;
    const int plane = blockIdx.x;          // b*256 + c
    const int b     = plane >> 8;

    const unsigned* gb = bits + b * 800;
    #pragma unroll
    for (int k = 0; k < 3; ++k) s_bits[tid + k * 256] = gb[tid + k * 256];
    if (tid < 32) s_bits[768 + tid] = gb[768 + tid];
    __syncthreads();

    const f32x4* fp = feat + plane * 6400 + tid;
    f32x4*       op = out  + plane * 6400 + tid;

    #pragma unroll 5
    for (int i = 0; i < 25; ++i) {
        const unsigned u    = (unsigned)(i * 256 + tid);       // f32x4 index in plane
        const unsigned nib  = s_bits[u >> 3] >> ((u & 7u) * 4u);
        f32x4 v = __builtin_nontemporal_load(fp + i * 256);
        f32x4 w;
        w.x = (nib & 1u) ? 1.1f : 0.1f;   // 1.0f+0.1f == 1.1f bitwise (0x3F8CCCCD)
        w.y = (nib & 2u) ? 1.1f : 0.1f;
        w.z = (nib & 4u) ? 1.1f : 0.1f;
        w.w = (nib & 8u) ? 1.1f : 0.1f;
        v *= w;
        __builtin_nontemporal_store(v, op + i * 256);
    }
}

extern "C" void kernel_launch(void* const* d_in, const int* in_sizes, int n_in,
                              void* d_out, int out_size, void* d_ws, size_t ws_size,
                              hipStream_t stream)
{
    const float* local_feat = (const float*)d_in[0];   // (8,256,160,160) fp32
    const float* att        = (const float*)d_in[1];   // (8,1,80,80) fp32
    // d_in[2] = spatial_scale (==2, fixed by problem shapes)

    float* out      = (float*)d_out;
    float* mask_out = out + 8 * 256 * 160 * 160;       // second output region

    upsample_select_kernel<<<8, 1024, 0, stream>>>(
        att, mask_out, (unsigned long long*)d_ws);

    apply_mask_kernel<<<2048, 256, 0, stream>>>(
        (const f32x4*)local_feat, (const unsigned*)d_ws, (f32x4*)out);
}

// Round 7
// 96.530 us; speedup vs baseline: 1.2589x; 1.0730x over previous
//
#include <hip/hip_runtime.h>

// RegionSelection: bilinear 2x upsample of attention map (8,1,80,80)->(8,1,160,160),
// per-batch rank-1921 threshold (k=int(0.3*6400)=1920, threshold=topv[:,k]),
// mask = up >= thr, weighted = local_feat*(mask+0.1).
// Outputs concatenated: weighted (8*256*160*160 fp32) then mask (8*160*160 fp32).
// d_ws: bit-packed mask, 400 ull per batch (1 bit per upsampled element).

#define NIN   6400    // 80*80
#define NUP   25600   // 160*160
#define KRANK 1921u   // (k+1)-th largest == topv[:, k]

typedef float f32x4 __attribute__((ext_vector_type(4)));

// Wave-parallel "find bin containing rank `rem_in` counting from the top" over
// NBINS histogram bins. Two-level: 64 chunk sums + shfl suffix-scan, then a
// parallel scan of the selected chunk's bins. No serial dependent-LDS chains.
// Executed by wave 0 (tid<64); writes {bin, remaining-within-bin} to s_bcast.
template <int NBINS>
__device__ inline void find_bin(const unsigned* s_hist, unsigned rem_in,
                                unsigned* s_bcast, int tid)
{
    constexpr int CHUNK = NBINS / 64;
    if (tid < 64) {
        const int lane = tid;
        unsigned csum = 0;
        #pragma unroll
        for (int k = 0; k < CHUNK; ++k) csum += s_hist[lane * CHUNK + k];
        unsigned suff = csum;                     // suffix sum: suff[l] = sum csum[l..63]
        #pragma unroll
        for (int off = 1; off < 64; off <<= 1) {
            unsigned o = __shfl_down(suff, off);
            if (lane + off < 64) suff += o;
        }
        unsigned suff_next = __shfl_down(suff, 1);
        if (lane == 63) suff_next = 0;
        const bool hit = (suff >= rem_in) & (suff_next < rem_in);  // exactly one lane
        unsigned long long bmask = __ballot(hit);
        const int src = (int)__builtin_ctzll(bmask);
        const unsigned r_chunk = __shfl(rem_in - suff_next, src);  // rank within chunk
        const int      cbase   = src * CHUNK;
        unsigned h = (lane < CHUNK) ? s_hist[cbase + lane] : 0u;
        unsigned ssum = h;
        #pragma unroll
        for (int off = 1; off < CHUNK; off <<= 1) {
            unsigned o = __shfl_down(ssum, off);
            if (lane + off < CHUNK) ssum += o;
        }
        unsigned ssum_next = __shfl_down(ssum, 1);
        if (lane >= CHUNK - 1) ssum_next = 0;
        const bool hit2 = (lane < CHUNK) & (ssum >= r_chunk) & (ssum_next < r_chunk);
        if (hit2) {
            s_bcast[0] = (unsigned)(cbase + lane);
            s_bcast[1] = r_chunk - ssum_next;
        }
    }
}

__global__ __launch_bounds__(1024) void upsample_select_kernel(
    const float* __restrict__ att, float* __restrict__ mask_out,
    unsigned long long* __restrict__ ws_bits)
{
    __shared__ float    s_in[NIN];
    __shared__ unsigned s_hist[2048];
    __shared__ unsigned s_bcast[2];

    const int b   = blockIdx.x;
    const int tid = threadIdx.x;

    const float* in = att + b * NIN;
    for (int i = tid; i < NIN; i += 1024) s_in[i] = in[i];
    __syncthreads();

    // bilinear 2x upsample, half-pixel centers; weights exactly {0.75,0.25};
    // boundary rows/cols clamp to the edge pixel. (validated absmax==0)
    unsigned ub[25];
    #pragma unroll
    for (int j = 0; j < 25; ++j) {
        int i = j * 1024 + tid;
        int r = i / 160;
        int c = i - r * 160;
        int y0, y1; float wy;
        if (r == 0)        { y0 = 0;  y1 = 0;  wy = 0.0f; }
        else if (r == 159) { y0 = 79; y1 = 79; wy = 0.0f; }
        else { float y = 0.5f * (float)r - 0.25f; y0 = (int)y; y1 = y0 + 1; wy = y - (float)y0; }
        int x0, x1; float wx;
        if (c == 0)        { x0 = 0;  x1 = 0;  wx = 0.0f; }
        else if (c == 159) { x0 = 79; x1 = 79; wx = 0.0f; }
        else { float x = 0.5f * (float)c - 0.25f; x0 = (int)x; x1 = x0 + 1; wx = x - (float)x0; }
        float top = s_in[y0 * 80 + x0] * (1.0f - wx) + s_in[y0 * 80 + x1] * wx;
        float bot = s_in[y1 * 80 + x0] * (1.0f - wx) + s_in[y1 * 80 + x1] * wx;
        float v   = top * (1.0f - wy) + bot * wy;
        ub[j] = __float_as_uint(v);   // v in [0,1) -> uint order == float order
    }

    // ---- exact radix select, 3 passes: bits [30:20], [19:10], [9:0] ----
    for (int i = tid; i < 2048; i += 1024) s_hist[i] = 0;
    __syncthreads();
    #pragma unroll
    for (int j = 0; j < 25; ++j) atomicAdd(&s_hist[ub[j] >> 20], 1u);  // <0x3F8 < 2048
    __syncthreads();
    find_bin<2048>(s_hist, KRANK, s_bcast, tid);
    __syncthreads();
    const unsigned p1  = s_bcast[0];
    unsigned       rem = s_bcast[1];
    __syncthreads();

    for (int i = tid; i < 1024; i += 1024) s_hist[i] = 0;
    __syncthreads();
    #pragma unroll
    for (int j = 0; j < 25; ++j) {
        unsigned u = ub[j];
        if ((u >> 20) == p1) atomicAdd(&s_hist[(u >> 10) & 1023u], 1u);
    }
    __syncthreads();
    find_bin<1024>(s_hist, rem, s_bcast, tid);
    __syncthreads();
    const unsigned pref2 = (p1 << 10) | s_bcast[0];
    rem = s_bcast[1];
    __syncthreads();

    for (int i = tid; i < 1024; i += 1024) s_hist[i] = 0;
    __syncthreads();
    #pragma unroll
    for (int j = 0; j < 25; ++j) {
        unsigned u = ub[j];
        if ((u >> 10) == pref2) atomicAdd(&s_hist[u & 1023u], 1u);
    }
    __syncthreads();
    find_bin<1024>(s_hist, rem, s_bcast, tid);
    __syncthreads();
    const unsigned thr_bits = (pref2 << 10) | s_bcast[0];

    // mask outputs: fp32 plane (required output) + bit-packed plane (for the
    // streaming kernel). Same values, same >= comparison -> identical set.
    float*              mptr  = mask_out + b * NUP;
    unsigned long long* wbptr = ws_bits + b * 400;   // 400 ull = 25600 bits
    const int lane = tid & 63;
    const int wv   = tid >> 6;
    #pragma unroll
    for (int j = 0; j < 25; ++j) {
        const bool sel = (ub[j] >= thr_bits);
        mptr[j * 1024 + tid] = sel ? 1.0f : 0.0f;
        unsigned long long bal = __ballot(sel);     // bit i = element j*1024+wv*64+i
        if (lane == 0) wbptr[j * 16 + wv] = bal;
    }
}

// weighted = local_feat * (mask + 0.1).
// One block per (b,c) plane; plane's bit-packed mask preloaded into LDS
// (3.2 KB). nt LOAD (read-once, keep L2 clean) + PLAIN store (the harness
// fills sustain 7 TB/s with plain stores; this round A/Bs nt-store vs plain).
__global__ __launch_bounds__(256) void apply_mask_kernel(
    const f32x4* __restrict__ feat, const unsigned* __restrict__ bits,
    f32x4* __restrict__ out)
{
    __shared__ unsigned s_bits[800];

    const int tid   = threadIdx.x;
    const int plane = blockIdx.x;          // b*256 + c
    const int b     = plane >> 8;

    const unsigned* gb = bits + b * 800;
    #pragma unroll
    for (int k = 0; k < 3; ++k) s_bits[tid + k * 256] = gb[tid + k * 256];
    if (tid < 32) s_bits[768 + tid] = gb[768 + tid];
    __syncthreads();

    const f32x4* fp = feat + plane * 6400 + tid;
    f32x4*       op = out  + plane * 6400 + tid;

    #pragma unroll 5
    for (int i = 0; i < 25; ++i) {
        const unsigned u    = (unsigned)(i * 256 + tid);       // f32x4 index in plane
        const unsigned nib  = s_bits[u >> 3] >> ((u & 7u) * 4u);
        f32x4 v = __builtin_nontemporal_load(fp + i * 256);
        f32x4 w;
        w.x = (nib & 1u) ? 1.1f : 0.1f;   // 1.0f+0.1f == 1.1f bitwise (0x3F8CCCCD)
        w.y = (nib & 2u) ? 1.1f : 0.1f;
        w.z = (nib & 4u) ? 1.1f : 0.1f;
        w.w = (nib & 8u) ? 1.1f : 0.1f;
        v *= w;
        op[i * 256] = v;                  // plain store (A/B vs round-6 nt store)
    }
}

extern "C" void kernel_launch(void* const* d_in, const int* in_sizes, int n_in,
                              void* d_out, int out_size, void* d_ws, size_t ws_size,
                              hipStream_t stream)
{
    const float* local_feat = (const float*)d_in[0];   // (8,256,160,160) fp32
    const float* att        = (const float*)d_in[1];   // (8,1,80,80) fp32
    // d_in[2] = spatial_scale (==2, fixed by problem shapes)

    float* out      = (float*)d_out;
    float* mask_out = out + 8 * 256 * 160 * 160;       // second output region

    upsample_select_kernel<<<8, 1024, 0, stream>>>(
        att, mask_out, (unsigned long long*)d_ws);

    apply_mask_kernel<<<2048, 256, 0, stream>>>(
        (const f32x4*)local_feat, (const unsigned*)d_ws, (f32x4*)out);
}